// Round 5
// baseline (708.298 us; speedup 1.0000x reference)
//
#include <hip/hip_runtime.h>
#include <hip/hip_cooperative_groups.h>

namespace cg = cooperative_groups;

#define NN 1000
#define NE 64000
#define HH 256
#define GRID 256

typedef _Float16 half8 __attribute__((ext_vector_type(8)));
typedef float floatx4 __attribute__((ext_vector_type(4)));

struct Args {
    const float* x;
    const int* ei;
    const float* w0[5]; const float* b0[5];
    const float* w1[5]; const float* b1[5];
    int* counts; int* cursor; int* ssrc; int* sdst;
    _Float16* node_ab; float* aggA; float* aggB;
    _Float16* wnode; _Float16* w2h;
    float* out;
};

// wnode[l]: [512][256] rows 0..255 = (A-B), rows 256..511 = B  (A=w0[:,:D], B=w0[:,D:])
// w2h[l]:   [256][256] = w1 cast to fp16
__device__ inline void prep_dev(const Args& a, int gtid, int gstride) {
    for (int l = 0; l < 5; l++) {
        int D = l ? 256 : 128;
        int sh = l ? 8 : 7;
        const float* w0 = a.w0[l];
        _Float16* wn = a.wnode + l * 512 * 256;
        for (int i = gtid; i < 512 * D; i += gstride) {
            int n = i >> sh, k = i & (D - 1);
            float v = (n < 256) ? (w0[n * 2 * D + k] - w0[n * 2 * D + D + k])
                                : w0[(n - 256) * 2 * D + D + k];
            wn[n * 256 + k] = (_Float16)v;
        }
        const float* w1 = a.w1[l];
        _Float16* w2 = a.w2h + l * 256 * 256;
        for (int i = gtid; i < 256 * 256; i += gstride)
            w2[i] = (_Float16)w1[i];
    }
}

// C = X[M,Kd] @ Wn[512,Kd]^T, 16x128 tile per block (252 tiles), loads hoisted.
template <int NK>
__device__ inline void node_tile(const float* __restrict__ X,
                                 const _Float16* __restrict__ Wn, const float* __restrict__ b0,
                                 _Float16* __restrict__ out, int bid) {
    const int Kd = NK * 32;
    int t = threadIdx.x;
    int wave = t >> 6, lane = t & 63;
    int q = lane >> 4, mn = lane & 15;
    int m0 = (bid % 63) * 16;
    int n0 = (bid / 63) * 128 + wave * 32;
    int rr = m0 + mn;
    if (rr >= NN) rr = NN - 1;

    half8 afa[NK];
    half8 bfa[NK][2];
#pragma unroll
    for (int kk = 0; kk < NK; kk++) {
        int ka = kk * 32 + q * 8;
        const float* p = X + (size_t)rr * Kd + ka;
        floatx4 x0 = *(const floatx4*)p;
        floatx4 x1 = *(const floatx4*)(p + 4);
        half8 aa;
#pragma unroll
        for (int j = 0; j < 4; j++) { aa[j] = (_Float16)x0[j]; aa[4 + j] = (_Float16)x1[j]; }
        afa[kk] = aa;
        bfa[kk][0] = *(const half8*)(Wn + (size_t)(n0 + mn) * 256 + ka);
        bfa[kk][1] = *(const half8*)(Wn + (size_t)(n0 + 16 + mn) * 256 + ka);
    }
    floatx4 acc[2] = {};
#pragma unroll
    for (int kk = 0; kk < NK; kk++) {
        acc[0] = __builtin_amdgcn_mfma_f32_16x16x32_f16(afa[kk], bfa[kk][0], acc[0], 0, 0, 0);
        acc[1] = __builtin_amdgcn_mfma_f32_16x16x32_f16(afa[kk], bfa[kk][1], acc[1], 0, 0, 0);
    }
#pragma unroll
    for (int nt = 0; nt < 2; nt++) {
        int col = n0 + nt * 16 + mn;
        float bias = (col < 256) ? b0[col] : 0.f;
#pragma unroll
        for (int r2 = 0; r2 < 4; r2++) {
            int orow = m0 + q * 4 + r2;
            if (orow < NN)
                out[(size_t)orow * 512 + col] = (_Float16)(acc[nt][r2] + bias);
        }
    }
}

__device__ inline void zero_dev(float* p, int n4, int gtid, int gstride) {
    floatx4* p4 = (floatx4*)p;
    floatx4 z = {0.f, 0.f, 0.f, 0.f};
    for (int i = gtid; i < n4; i += gstride) p4[i] = z;
}

// 64 sorted edges x 256 cols per tile. h1 = relu(a[dst]+b[src]) in XOR-swizzled
// LDS; K-loop with 1-deep W2 register prefetch; epilogue merges same-dst runs
// then atomicMax(uint) (values >= 0, agg zero-init).
__device__ inline void edge_phase(const _Float16* __restrict__ node_ab,
                                  const int* __restrict__ ssrc, const int* __restrict__ sdst,
                                  const _Float16* __restrict__ W2, const float* __restrict__ b2,
                                  float* __restrict__ agg,
                                  _Float16* h1, int* sd, int bid, int t) {
    int wave = t >> 6, lane = t & 63;
    int q = lane >> 4, mn = lane & 15;
    int n0 = wave * 64;
    for (int tile = bid; tile < NE / 64; tile += GRID) {
        __syncthreads();  // protect h1/sd reuse across tiles
        int e0 = tile * 64;
        half8 bf_cur[4], bf_nxt[4];
#pragma unroll
        for (int nt = 0; nt < 4; nt++)
            bf_cur[nt] = *(const half8*)(W2 + (size_t)(n0 + nt * 16 + mn) * 256 + q * 8);
        if (t < 64) sd[t] = sdst[e0 + t];
        {   // staging: all 16 loads in flight
            int row = t & 63;
            int cb = (t >> 6) * 8;
            int dn = sdst[e0 + row], sn = ssrc[e0 + row];
            const _Float16* pa = node_ab + (size_t)dn * 512 + cb * 8;
            const _Float16* pb = node_ab + (size_t)sn * 512 + 256 + cb * 8;
            half8 av[8], bv[8];
#pragma unroll
            for (int i = 0; i < 8; i++) av[i] = *(const half8*)(pa + i * 8);
#pragma unroll
            for (int i = 0; i < 8; i++) bv[i] = *(const half8*)(pb + i * 8);
#pragma unroll
            for (int i = 0; i < 8; i++) {
                int c = cb + i;
                int p = (c & ~7) | ((c ^ row) & 7);  // conflict-free b128 swizzle
                half8 hv = av[i] + bv[i];
#pragma unroll
                for (int j = 0; j < 8; j++) hv[j] = hv[j] > (_Float16)0 ? hv[j] : (_Float16)0;
                *(half8*)(&h1[row * 256 + p * 8]) = hv;
            }
        }
        __syncthreads();

        floatx4 acc[4][4] = {};
#pragma unroll
        for (int kk = 0; kk < 8; kk++) {
            if (kk < 7) {
#pragma unroll
                for (int nt = 0; nt < 4; nt++)
                    bf_nxt[nt] = *(const half8*)(W2 + (size_t)(n0 + nt * 16 + mn) * 256 + (kk + 1) * 32 + q * 8);
            }
            half8 af[4];
#pragma unroll
            for (int mt = 0; mt < 4; mt++) {
                int r = mt * 16 + mn;
                int c = kk * 4 + q;
                int p = (c & ~7) | ((c ^ r) & 7);
                af[mt] = *(const half8*)(&h1[r * 256 + p * 8]);
            }
#pragma unroll
            for (int mt = 0; mt < 4; mt++)
#pragma unroll
                for (int nt = 0; nt < 4; nt++)
                    acc[mt][nt] = __builtin_amdgcn_mfma_f32_16x16x32_f16(af[mt], bf_cur[nt], acc[mt][nt], 0, 0, 0);
            if (kk < 7) {
#pragma unroll
                for (int nt = 0; nt < 4; nt++) bf_cur[nt] = bf_nxt[nt];
            }
        }

#pragma unroll
        for (int nt = 0; nt < 4; nt++) {
            int col = n0 + nt * 16 + mn;
            float bias = b2[col];
            int curd = -1;
            float curv = 0.f;
#pragma unroll
            for (int mt = 0; mt < 4; mt++) {
#pragma unroll
                for (int r2 = 0; r2 < 4; r2++) {
                    int er = mt * 16 + q * 4 + r2;  // monotone -> sorted runs merge
                    int d = sd[er];
                    float v = acc[mt][nt][r2] + bias;
                    v = v > 0.f ? v : 0.f;
                    if (d != curd) {
                        if (curd >= 0 && curv > 0.f)
                            atomicMax((unsigned int*)(agg + (size_t)curd * HH + col), __float_as_uint(curv));
                        curd = d;
                        curv = v;
                    } else {
                        curv = fmaxf(curv, v);
                    }
                }
            }
            if (curd >= 0 && curv > 0.f)
                atomicMax((unsigned int*)(agg + (size_t)curd * HH + col), __float_as_uint(curv));
        }
    }
}

__global__ __launch_bounds__(256, 2) void mega(Args a) {
    __shared__ _Float16 h1[64 * 256];
    __shared__ int sd[64];
    cg::grid_group grid = cg::this_grid();
    int bid = blockIdx.x, t = threadIdx.x;
    int gtid = bid * 256 + t, gstride = GRID * 256;

    // P0: zero counts + convert weights to fp16
    if (bid == 0)
        for (int i = t; i < 1024; i += 256) a.counts[i] = 0;
    prep_dev(a, gtid, gstride);
    grid.sync();

    // P1: dst histogram + layer-0 node GEMM + zero aggA
    for (int e = gtid; e < NE; e += gstride)
        atomicAdd(&a.counts[a.ei[NE + e] & 1023], 1);
    if (bid < 252) node_tile<4>(a.x, a.wnode, a.b0[0], a.node_ab, bid);
    zero_dev(a.aggA, NN * HH / 4, gtid, gstride);
    grid.sync();

    // P2: exclusive prefix scan over counts (block 0 only)
    if (bid == 0) {
        int* s = (int*)h1;
        int base = t * 4;
        int c4[4]; int sum = 0;
#pragma unroll
        for (int j = 0; j < 4; j++) { c4[j] = a.counts[base + j]; sum += c4[j]; }
        s[t] = sum;
        __syncthreads();
        for (int d = 1; d < 256; d <<= 1) {
            int v = (t >= d) ? s[t - d] : 0;
            __syncthreads();
            s[t] += v;
            __syncthreads();
        }
        int run = (t > 0) ? s[t - 1] : 0;
#pragma unroll
        for (int j = 0; j < 4; j++) { a.cursor[base + j] = run; run += c4[j]; }
    }
    grid.sync();

    // P3: scatter edges into dst-sorted order
    for (int e = gtid; e < NE; e += gstride) {
        int sn = a.ei[e] & 1023, d = a.ei[NE + e] & 1023;
        int pos = atomicAdd(&a.cursor[d], 1);
        if (pos < NE) {
            a.ssrc[pos] = sn;
            a.sdst[pos] = d;
        }
    }
    grid.sync();

    // 5 EdgeConv layers
    float* aggs[5] = {a.aggA, a.aggB, a.aggA, a.aggB, a.out};
    for (int l = 0; l < 5; l++) {
        edge_phase(a.node_ab, a.ssrc, a.sdst, a.w2h + l * 65536, a.b1[l], aggs[l], h1, sd, bid, t);
        if (l < 4) {
            grid.sync();
            if (bid < 252) node_tile<8>(aggs[l], a.wnode + (size_t)(l + 1) * 131072, a.b0[l + 1], a.node_ab, bid);
            zero_dev(aggs[l + 1], NN * HH / 4, gtid, gstride);
            grid.sync();
        }
    }
}

extern "C" void kernel_launch(void* const* d_in, const int* in_sizes, int n_in,
                              void* d_out, int out_size, void* d_ws, size_t ws_size,
                              hipStream_t stream) {
    Args a;
    a.x = (const float*)d_in[0];
    a.ei = (const int*)d_in[1];  // int32 per harness contract
    for (int l = 0; l < 5; l++) {
        a.w0[l] = (const float*)d_in[2 + 4 * l];
        a.b0[l] = (const float*)d_in[3 + 4 * l];
        a.w1[l] = (const float*)d_in[4 + 4 * l];
        a.b1[l] = (const float*)d_in[5 + 4 * l];
    }
    a.ssrc = (int*)d_ws;                             // 256 KB
    a.sdst = a.ssrc + NE;                            // 256 KB
    a.counts = a.sdst + NE;                          // 4 KB
    a.cursor = a.counts + 1024;                      // 4 KB
    a.node_ab = (_Float16*)(a.cursor + 1024);        // [1024][512] fp16, 1 MB
    a.aggA = (float*)(a.node_ab + 1024 * 512);       // 1 MB
    a.aggB = a.aggA + NN * HH;                       // 1 MB
    a.wnode = (_Float16*)(a.aggB + NN * HH);         // 1.25 MB
    a.w2h = a.wnode + 5 * 512 * 256;                 // 0.63 MB
    a.out = (float*)d_out;

    void* kargs[] = {(void*)&a};
    hipLaunchCooperativeKernel(mega, dim3(GRID), dim3(256), kargs, 0, stream);
}

// Round 6
// 337.625 us; speedup vs baseline: 2.0979x; 2.0979x over previous
//
#include <hip/hip_runtime.h>

#define NN 1000
#define NE 64000
#define HH 256

typedef _Float16 half8 __attribute__((ext_vector_type(8)));
typedef float floatx4 __attribute__((ext_vector_type(4)));

struct PrepArgs { const float* w0[5]; const float* w1[5]; };

// ---------- fused prep: weight convert + dst histogram + zero aggA ----------
// wnode[l]: [512][256] rows 0..255 = (A-B), rows 256..511 = B  (A=w0[:,:D], B=w0[:,D:])
// w2h[l]:   [256][256] = w1 cast to fp16
__global__ __launch_bounds__(256) void k_prep(PrepArgs pa, const int* __restrict__ ei,
                                              _Float16* wnode, _Float16* w2h,
                                              int* counts, float* aggA) {
    int gtid = blockIdx.x * 256 + threadIdx.x;
    int gstride = gridDim.x * 256;
    for (int i = gtid; i < 1024; i += gstride) counts[i] = 0;
    for (int l = 0; l < 5; l++) {
        int D = l ? 256 : 128;
        const float* w0 = pa.w0[l];
        _Float16* wn = wnode + l * 512 * 256;
        for (int i = gtid; i < 512 * D; i += gstride) {
            int n = i / D, k = i - n * D;
            float v = (n < 256) ? (w0[n * 2 * D + k] - w0[n * 2 * D + D + k])
                                : w0[(n - 256) * 2 * D + D + k];
            wn[n * 256 + k] = (_Float16)v;
        }
        const float* w1 = pa.w1[l];
        _Float16* w2 = w2h + l * 256 * 256;
        for (int i = gtid; i < 256 * 256; i += gstride)
            w2[i] = (_Float16)w1[i];
    }
    floatx4 z = {0.f, 0.f, 0.f, 0.f};
    floatx4* p4 = (floatx4*)aggA;
    for (int i = gtid; i < NN * HH / 4; i += gstride) p4[i] = z;
    // histogram last: counts[] zeroing above is done by the same blocks that
    // use it only via atomics below, but other blocks may race -> use atomic-safe
    // ordering: all blocks zero disjoint ranges before any atomicAdd lands on
    // them only if same block... NOT guaranteed across blocks, so do hist in a
    // separate grid pass? Instead: counts zeroing is done only by gtid<1024
    // (first 4 blocks) and hist waits. To stay single-kernel and safe, hist is
    // guarded per-block: do it in dispatch-order-independent way via separate
    // counts2 region is overkill -- instead hist runs in k_scan's grid? No:
    // simplest safe fix: hist here but on counts preset by a device-side loop
    // in THIS block for its own range is unsafe. => hist moved to k_scan's
    // sibling blocks (see k_scan_node0).
}

// C = X[M,Kd] @ Wn[512,Kd]^T, 16x128 tile per block (252 tiles), loads hoisted.
template <int NK>
__device__ inline void node_tile(const float* __restrict__ X,
                                 const _Float16* __restrict__ Wn, const float* __restrict__ b0,
                                 _Float16* __restrict__ out, int bid) {
    const int Kd = NK * 32;
    int t = threadIdx.x;
    int wave = t >> 6, lane = t & 63;
    int q = lane >> 4, mn = lane & 15;
    int m0 = (bid % 63) * 16;
    int n0 = (bid / 63) * 128 + wave * 32;
    int rr = m0 + mn;
    if (rr >= NN) rr = NN - 1;

    half8 afa[NK];
    half8 bfa[NK][2];
#pragma unroll
    for (int kk = 0; kk < NK; kk++) {
        int ka = kk * 32 + q * 8;
        const float* p = X + (size_t)rr * Kd + ka;
        floatx4 x0 = *(const floatx4*)p;
        floatx4 x1 = *(const floatx4*)(p + 4);
        half8 aa;
#pragma unroll
        for (int j = 0; j < 4; j++) { aa[j] = (_Float16)x0[j]; aa[4 + j] = (_Float16)x1[j]; }
        afa[kk] = aa;
        bfa[kk][0] = *(const half8*)(Wn + (size_t)(n0 + mn) * 256 + ka);
        bfa[kk][1] = *(const half8*)(Wn + (size_t)(n0 + 16 + mn) * 256 + ka);
    }
    floatx4 acc[2] = {};
#pragma unroll
    for (int kk = 0; kk < NK; kk++) {
        acc[0] = __builtin_amdgcn_mfma_f32_16x16x32_f16(afa[kk], bfa[kk][0], acc[0], 0, 0, 0);
        acc[1] = __builtin_amdgcn_mfma_f32_16x16x32_f16(afa[kk], bfa[kk][1], acc[1], 0, 0, 0);
    }
#pragma unroll
    for (int nt = 0; nt < 2; nt++) {
        int col = n0 + nt * 16 + mn;
        float bias = (col < 256) ? b0[col] : 0.f;
#pragma unroll
        for (int r2 = 0; r2 < 4; r2++) {
            int orow = m0 + q * 4 + r2;
            if (orow < NN)
                out[(size_t)orow * 512 + col] = (_Float16)(acc[nt][r2] + bias);
        }
    }
}

// block 0: dst histogram (counts zeroed in k_prep); blocks 1..252: layer-0 node GEMM
__global__ __launch_bounds__(256) void k_hist_node0(const int* __restrict__ ei,
                                                    int* __restrict__ counts,
                                                    const float* __restrict__ X,
                                                    const _Float16* __restrict__ Wn,
                                                    const float* __restrict__ b0,
                                                    _Float16* __restrict__ out) {
    int bid = blockIdx.x;
    if (bid < 4) {
        for (int e = bid * 256 + threadIdx.x; e < NE; e += 4 * 256)
            atomicAdd(&counts[ei[NE + e] & 1023], 1);
    } else {
        node_tile<4>(X, Wn, b0, out, bid - 4);
    }
}

// single block: exclusive prefix scan counts -> cursor
__global__ __launch_bounds__(256) void k_scan(const int* __restrict__ counts,
                                              int* __restrict__ cursor) {
    __shared__ int s[256];
    int t = threadIdx.x;
    int base = t * 4;
    int c4[4]; int sum = 0;
#pragma unroll
    for (int j = 0; j < 4; j++) { c4[j] = counts[base + j]; sum += c4[j]; }
    s[t] = sum;
    __syncthreads();
    for (int d = 1; d < 256; d <<= 1) {
        int v = (t >= d) ? s[t - d] : 0;
        __syncthreads();
        s[t] += v;
        __syncthreads();
    }
    int run = (t > 0) ? s[t - 1] : 0;
#pragma unroll
    for (int j = 0; j < 4; j++) { cursor[base + j] = run; run += c4[j]; }
}

__global__ __launch_bounds__(256) void k_scatter(const int* __restrict__ ei,
                                                 int* __restrict__ cursor,
                                                 int* __restrict__ ssrc, int* __restrict__ sdst) {
    int e = blockIdx.x * blockDim.x + threadIdx.x;
    if (e < NE) {
        int s = ei[e] & 1023, d = ei[NE + e] & 1023;
        int pos = atomicAdd(&cursor[d], 1);
        if (pos < NE) {
            ssrc[pos] = s;
            sdst[pos] = d;
        }
    }
}

// blocks 0..251: node GEMM layer l+1 (reads agg_in); blocks 252..: zero agg_next
// (agg_in != agg_next: ping-pong buffers)
__global__ __launch_bounds__(256) void k_node_zero(const float* __restrict__ agg_in,
                                                   const _Float16* __restrict__ Wn,
                                                   const float* __restrict__ b0,
                                                   _Float16* __restrict__ out,
                                                   float* __restrict__ agg_next) {
    int bid = blockIdx.x;
    if (bid < 252) {
        node_tile<8>(agg_in, Wn, b0, out, bid);
    } else {
        floatx4 z = {0.f, 0.f, 0.f, 0.f};
        floatx4* p4 = (floatx4*)agg_next;
        for (int i = (bid - 252) * 256 + (int)threadIdx.x; i < NN * HH / 4; i += 64 * 256)
            p4[i] = z;
    }
}

// 64 sorted edges x 256 cols. h1 = relu(a[dst]+b[src]) in XOR-swizzled LDS;
// K-loop: 4 W2 fragment loads batched per k-step (TLP hides latency at 16
// waves/CU); epilogue merges same-dst runs then atomicMax(uint).
__global__ __launch_bounds__(256, 4) void edge_gemm(const _Float16* __restrict__ node_ab,
                          const int* __restrict__ ssrc, const int* __restrict__ sdst,
                          const _Float16* __restrict__ W2, const float* __restrict__ b2,
                          float* __restrict__ agg) {
    __shared__ _Float16 h1[64 * 256];
    __shared__ int sd[64];
    int t = threadIdx.x;
    int e0 = blockIdx.x * 64;
    int wave = t >> 6, lane = t & 63;
    int q = lane >> 4, mn = lane & 15;
    int n0 = wave * 64;

    if (t < 64) sd[t] = sdst[e0 + t];
    {   // staging: all 16 loads in flight
        int row = t & 63;
        int cb = (t >> 6) * 8;
        int dn = sdst[e0 + row], sn = ssrc[e0 + row];
        const _Float16* pa = node_ab + (size_t)dn * 512 + cb * 8;
        const _Float16* pb = node_ab + (size_t)sn * 512 + 256 + cb * 8;
        half8 av[8], bv[8];
#pragma unroll
        for (int i = 0; i < 8; i++) av[i] = *(const half8*)(pa + i * 8);
#pragma unroll
        for (int i = 0; i < 8; i++) bv[i] = *(const half8*)(pb + i * 8);
#pragma unroll
        for (int i = 0; i < 8; i++) {
            int c = cb + i;
            int p = (c & ~7) | ((c ^ row) & 7);  // balanced b128 bank classes
            half8 hv = av[i] + bv[i];
#pragma unroll
            for (int j = 0; j < 8; j++) hv[j] = hv[j] > (_Float16)0 ? hv[j] : (_Float16)0;
            *(half8*)(&h1[row * 256 + p * 8]) = hv;
        }
    }
    __syncthreads();

    floatx4 acc[4][4] = {};
#pragma unroll
    for (int kk = 0; kk < 8; kk++) {
        half8 bf[4];
#pragma unroll
        for (int nt = 0; nt < 4; nt++)
            bf[nt] = *(const half8*)(W2 + (size_t)(n0 + nt * 16 + mn) * 256 + kk * 32 + q * 8);
        half8 af[4];
#pragma unroll
        for (int mt = 0; mt < 4; mt++) {
            int r = mt * 16 + mn;
            int c = kk * 4 + q;
            int p = (c & ~7) | ((c ^ r) & 7);
            af[mt] = *(const half8*)(&h1[r * 256 + p * 8]);
        }
#pragma unroll
        for (int mt = 0; mt < 4; mt++)
#pragma unroll
            for (int nt = 0; nt < 4; nt++)
                acc[mt][nt] = __builtin_amdgcn_mfma_f32_16x16x32_f16(af[mt], bf[nt], acc[mt][nt], 0, 0, 0);
    }

#pragma unroll
    for (int nt = 0; nt < 4; nt++) {
        int col = n0 + nt * 16 + mn;
        float bias = b2[col];
        int curd = -1;
        float curv = 0.f;
#pragma unroll
        for (int mt = 0; mt < 4; mt++) {
#pragma unroll
            for (int r2 = 0; r2 < 4; r2++) {
                int er = mt * 16 + q * 4 + r2;  // monotone -> sorted runs merge
                int d = sd[er];
                float v = acc[mt][nt][r2] + bias;
                v = v > 0.f ? v : 0.f;
                if (d != curd) {
                    if (curd >= 0 && curv > 0.f)
                        atomicMax((unsigned int*)(agg + (size_t)curd * HH + col), __float_as_uint(curv));
                    curd = d;
                    curv = v;
                } else {
                    curv = fmaxf(curv, v);
                }
            }
        }
        if (curd >= 0 && curv > 0.f)
            atomicMax((unsigned int*)(agg + (size_t)curd * HH + col), __float_as_uint(curv));
    }
}

extern "C" void kernel_launch(void* const* d_in, const int* in_sizes, int n_in,
                              void* d_out, int out_size, void* d_ws, size_t ws_size,
                              hipStream_t stream) {
    const float* x = (const float*)d_in[0];
    const int* ei = (const int*)d_in[1];  // int32 per harness contract
    PrepArgs pa;
    const float* b0s[5];
    const float* b1s[5];
    for (int l = 0; l < 5; l++) {
        pa.w0[l] = (const float*)d_in[2 + 4 * l];
        b0s[l] = (const float*)d_in[3 + 4 * l];
        pa.w1[l] = (const float*)d_in[4 + 4 * l];
        b1s[l] = (const float*)d_in[5 + 4 * l];
    }

    int* ssrc = (int*)d_ws;                              // 256 KB
    int* sdst = ssrc + NE;                               // 256 KB
    int* counts = sdst + NE;                             // 4 KB
    int* cursor = counts + 1024;                         // 4 KB
    _Float16* node_ab = (_Float16*)(cursor + 1024);      // [1024][512] fp16, 1 MB
    float* aggA = (float*)(node_ab + 1024 * 512);        // 1 MB
    float* aggB = aggA + NN * HH;                        // 1 MB
    _Float16* wnode = (_Float16*)(aggB + NN * HH);       // 1.25 MB
    _Float16* w2h = wnode + 5 * 512 * 256;               // 0.63 MB

    // 1: weights->fp16, zero counts, zero aggA
    hipLaunchKernelGGL(k_prep, dim3(256), dim3(256), 0, stream, pa, ei, wnode, w2h, counts, aggA);
    // 2: hist + layer-0 node GEMM
    hipLaunchKernelGGL(k_hist_node0, dim3(256), dim3(256), 0, stream, ei, counts, x, wnode, b0s[0], node_ab);
    // 3: scan
    hipLaunchKernelGGL(k_scan, dim3(1), dim3(256), 0, stream, counts, cursor);
    // 4: scatter
    hipLaunchKernelGGL(k_scatter, dim3((NE + 255) / 256), dim3(256), 0, stream, ei, cursor, ssrc, sdst);

    float* aggs[5] = {aggA, aggB, aggA, aggB, (float*)d_out};
    for (int l = 0; l < 5; l++) {
        hipLaunchKernelGGL(edge_gemm, dim3(NE / 64), dim3(256), 0, stream,
                           node_ab, ssrc, sdst, w2h + (size_t)l * 65536, b1s[l], aggs[l]);
        if (l < 4)
            hipLaunchKernelGGL(k_node_zero, dim3(252 + 64), dim3(256), 0, stream,
                               aggs[l], wnode + (size_t)(l + 1) * 131072, b0s[l + 1],
                               node_ab, aggs[l + 1]);
    }
}

// Round 7
// 292.535 us; speedup vs baseline: 2.4212x; 1.1541x over previous
//
#include <hip/hip_runtime.h>

#define NN 1000
#define NE 64000
#define HH 256

typedef _Float16 half8 __attribute__((ext_vector_type(8)));
typedef float floatx4 __attribute__((ext_vector_type(4)));

struct PrepArgs { const float* w0[5]; const float* w1[5]; };

// ---------------------------------------------------------------------------
// Weight pre-swizzle into MFMA B-fragment order so in-kernel fragment loads are
// lane-coalesced (base + lane*16B), 4 cache lines per wave instruction.
//
// node weights (per layer, KK = Kd/32, uniform 131072-halfs slot):
//   idx(slice,kk,nt,lane,j) = (((slice*KK+kk)*2+nt)*64+lane)*8+j
//   source row n = slice*32+nt*16+(lane&15), col k = kk*32+(lane>>4)*8+j
//   value: n<256 -> w0[n][k]-w0[n][D+k] (=A-B) ; else w0[n-256][D+k] (=B)
// W2 (per layer, 65536 halfs):
//   idx(ws,kk,nt,lane,j) = (((ws*8+kk)*4+nt)*64+lane)*8+j
//   source row = ws*64+nt*16+(lane&15), col = kk*32+(lane>>4)*8+j
// ---------------------------------------------------------------------------
__global__ __launch_bounds__(256) void k_prep(PrepArgs pa,
                                              _Float16* wnode, _Float16* w2h,
                                              int* counts, float* aggA) {
    int gtid = blockIdx.x * 256 + threadIdx.x;
    int gstride = gridDim.x * 256;
    for (int i = gtid; i < 1024; i += gstride) counts[i] = 0;
    for (int l = 0; l < 5; l++) {
        const int KK = l ? 8 : 4;
        const int D = KK * 32;
        const int lgKK = l ? 3 : 2;
        const float* w0 = pa.w0[l];
        _Float16* wn = wnode + l * 131072;
        for (int i = gtid; i < 16384 * KK; i += gstride) {
            int j = i & 7;
            int lane = (i >> 3) & 63;
            int nt = (i >> 9) & 1;
            int kk = (i >> 10) & (KK - 1);
            int slice = i >> (10 + lgKK);
            int mn = lane & 15, q = lane >> 4;
            int n = slice * 32 + nt * 16 + mn;
            int k = kk * 32 + q * 8 + j;
            float v = (n < 256) ? (w0[n * 2 * D + k] - w0[n * 2 * D + D + k])
                                : w0[(n - 256) * 2 * D + D + k];
            wn[i] = (_Float16)v;
        }
        const float* w1 = pa.w1[l];
        _Float16* w2 = w2h + l * 65536;
        for (int i = gtid; i < 65536; i += gstride) {
            int j = i & 7;
            int lane = (i >> 3) & 63;
            int nt = (i >> 9) & 3;
            int kk = (i >> 11) & 7;
            int ws = (i >> 14) & 3;
            int mn = lane & 15, q = lane >> 4;
            int row = ws * 64 + nt * 16 + mn;
            int col = kk * 32 + q * 8 + j;
            w2[i] = (_Float16)w1[row * 256 + col];
        }
    }
    floatx4 z = {0.f, 0.f, 0.f, 0.f};
    floatx4* p4 = (floatx4*)aggA;
    for (int i = gtid; i < NN * HH / 4; i += gstride) p4[i] = z;
}

// C = X[M,Kd] @ Wn^T, 16x128 tile per block (252 tiles); Wn in fragment order.
template <int NK>
__device__ inline void node_tile(const float* __restrict__ X,
                                 const _Float16* __restrict__ Wn, const float* __restrict__ b0,
                                 _Float16* __restrict__ out, int bid) {
    const int Kd = NK * 32;
    int t = threadIdx.x;
    int wave = t >> 6, lane = t & 63;
    int q = lane >> 4, mn = lane & 15;
    int m0 = (bid % 63) * 16;
    int n0 = (bid / 63) * 128 + wave * 32;
    int slice = (bid / 63) * 4 + wave;
    int rr = m0 + mn;
    if (rr >= NN) rr = NN - 1;

    half8 afa[NK];
    half8 bfa[NK][2];
#pragma unroll
    for (int kk = 0; kk < NK; kk++) {
        int ka = kk * 32 + q * 8;
        const float* p = X + (size_t)rr * Kd + ka;
        floatx4 x0 = *(const floatx4*)p;
        floatx4 x1 = *(const floatx4*)(p + 4);
        half8 aa;
#pragma unroll
        for (int j = 0; j < 4; j++) { aa[j] = (_Float16)x0[j]; aa[4 + j] = (_Float16)x1[j]; }
        afa[kk] = aa;
        bfa[kk][0] = *(const half8*)(Wn + (((slice * NK + kk) * 2 + 0) * 64 + lane) * 8);
        bfa[kk][1] = *(const half8*)(Wn + (((slice * NK + kk) * 2 + 1) * 64 + lane) * 8);
    }
    floatx4 acc[2] = {};
#pragma unroll
    for (int kk = 0; kk < NK; kk++) {
        acc[0] = __builtin_amdgcn_mfma_f32_16x16x32_f16(afa[kk], bfa[kk][0], acc[0], 0, 0, 0);
        acc[1] = __builtin_amdgcn_mfma_f32_16x16x32_f16(afa[kk], bfa[kk][1], acc[1], 0, 0, 0);
    }
#pragma unroll
    for (int nt = 0; nt < 2; nt++) {
        int col = n0 + nt * 16 + mn;
        float bias = (col < 256) ? b0[col] : 0.f;
#pragma unroll
        for (int r2 = 0; r2 < 4; r2++) {
            int orow = m0 + q * 4 + r2;
            if (orow < NN)
                out[(size_t)orow * 512 + col] = (_Float16)(acc[nt][r2] + bias);
        }
    }
}

// blocks 0..3: dst histogram; blocks 4..255: layer-0 node GEMM
__global__ __launch_bounds__(256) void k_hist_node0(const int* __restrict__ ei,
                                                    int* __restrict__ counts,
                                                    const float* __restrict__ X,
                                                    const _Float16* __restrict__ Wn,
                                                    const float* __restrict__ b0,
                                                    _Float16* __restrict__ out) {
    int bid = blockIdx.x;
    if (bid < 4) {
        for (int e = bid * 256 + threadIdx.x; e < NE; e += 4 * 256)
            atomicAdd(&counts[ei[NE + e] & 1023], 1);
    } else {
        node_tile<4>(X, Wn, b0, out, bid - 4);
    }
}

// single block: exclusive prefix scan counts -> cursor
__global__ __launch_bounds__(256) void k_scan(const int* __restrict__ counts,
                                              int* __restrict__ cursor) {
    __shared__ int s[256];
    int t = threadIdx.x;
    int base = t * 4;
    int c4[4]; int sum = 0;
#pragma unroll
    for (int j = 0; j < 4; j++) { c4[j] = counts[base + j]; sum += c4[j]; }
    s[t] = sum;
    __syncthreads();
    for (int d = 1; d < 256; d <<= 1) {
        int v = (t >= d) ? s[t - d] : 0;
        __syncthreads();
        s[t] += v;
        __syncthreads();
    }
    int run = (t > 0) ? s[t - 1] : 0;
#pragma unroll
    for (int j = 0; j < 4; j++) { cursor[base + j] = run; run += c4[j]; }
}

__global__ __launch_bounds__(256) void k_scatter(const int* __restrict__ ei,
                                                 int* __restrict__ cursor,
                                                 int* __restrict__ ssrc, int* __restrict__ sdst) {
    int e = blockIdx.x * blockDim.x + threadIdx.x;
    if (e < NE) {
        int s = ei[e] & 1023, d = ei[NE + e] & 1023;
        int pos = atomicAdd(&cursor[d], 1);
        if (pos < NE) {
            ssrc[pos] = s;
            sdst[pos] = d;
        }
    }
}

// blocks 0..251: node GEMM layer l+1 (reads agg_in); blocks 252..315: zero agg_next
__global__ __launch_bounds__(256) void k_node_zero(const float* __restrict__ agg_in,
                                                   const _Float16* __restrict__ Wn,
                                                   const float* __restrict__ b0,
                                                   _Float16* __restrict__ out,
                                                   float* __restrict__ agg_next) {
    int bid = blockIdx.x;
    if (bid < 252) {
        node_tile<8>(agg_in, Wn, b0, out, bid);
    } else {
        floatx4 z = {0.f, 0.f, 0.f, 0.f};
        floatx4* p4 = (floatx4*)agg_next;
        for (int i = (bid - 252) * 256 + (int)threadIdx.x; i < NN * HH / 4; i += 64 * 256)
            p4[i] = z;
    }
}

// 64 sorted edges x 256 cols. h1 = relu(a[dst]+b[src]) in XOR-swizzled LDS;
// W2 in fragment order -> coalesced b128 loads; epilogue merges same-dst runs
// then atomicMax(uint) into zero-initialized agg (values clamped >= 0).
__global__ __launch_bounds__(256, 4) void edge_gemm(const _Float16* __restrict__ node_ab,
                          const int* __restrict__ ssrc, const int* __restrict__ sdst,
                          const _Float16* __restrict__ W2, const float* __restrict__ b2,
                          float* __restrict__ agg) {
    __shared__ _Float16 h1[64 * 256];
    __shared__ int sd[64];
    int t = threadIdx.x;
    int e0 = blockIdx.x * 64;
    int wave = t >> 6, lane = t & 63;
    int q = lane >> 4, mn = lane & 15;
    int n0 = wave * 64;
    const _Float16* W2w = W2 + wave * 16384;  // this wave's fragment slice

    if (t < 64) sd[t] = sdst[e0 + t];
    {   // staging: all 16 gather loads in flight
        int row = t & 63;
        int cb = (t >> 6) * 8;
        int dn = sdst[e0 + row], sn = ssrc[e0 + row];
        const _Float16* pa = node_ab + (size_t)dn * 512 + cb * 8;
        const _Float16* pb = node_ab + (size_t)sn * 512 + 256 + cb * 8;
        half8 av[8], bv[8];
#pragma unroll
        for (int i = 0; i < 8; i++) av[i] = *(const half8*)(pa + i * 8);
#pragma unroll
        for (int i = 0; i < 8; i++) bv[i] = *(const half8*)(pb + i * 8);
#pragma unroll
        for (int i = 0; i < 8; i++) {
            int c = cb + i;
            int p = (c & ~7) | ((c ^ row) & 7);
            half8 hv = av[i] + bv[i];
#pragma unroll
            for (int j = 0; j < 8; j++) hv[j] = hv[j] > (_Float16)0 ? hv[j] : (_Float16)0;
            *(half8*)(&h1[row * 256 + p * 8]) = hv;
        }
    }
    __syncthreads();

    floatx4 acc[4][4] = {};
#pragma unroll
    for (int kk = 0; kk < 8; kk++) {
        half8 bf[4];
#pragma unroll
        for (int nt = 0; nt < 4; nt++)
            bf[nt] = *(const half8*)(W2w + (kk * 4 + nt) * 512 + lane * 8);  // coalesced
        half8 af[4];
#pragma unroll
        for (int mt = 0; mt < 4; mt++) {
            int r = mt * 16 + mn;
            int c = kk * 4 + q;
            int p = (c & ~7) | ((c ^ r) & 7);
            af[mt] = *(const half8*)(&h1[r * 256 + p * 8]);
        }
#pragma unroll
        for (int mt = 0; mt < 4; mt++)
#pragma unroll
            for (int nt = 0; nt < 4; nt++)
                acc[mt][nt] = __builtin_amdgcn_mfma_f32_16x16x32_f16(af[mt], bf[nt], acc[mt][nt], 0, 0, 0);
    }

#pragma unroll
    for (int nt = 0; nt < 4; nt++) {
        int col = n0 + nt * 16 + mn;
        float bias = b2[col];
        int curd = -1;
        float curv = 0.f;
#pragma unroll
        for (int mt = 0; mt < 4; mt++) {
#pragma unroll
            for (int r2 = 0; r2 < 4; r2++) {
                int er = mt * 16 + q * 4 + r2;  // monotone -> sorted runs merge
                int d = sd[er];
                float v = acc[mt][nt][r2] + bias;
                v = v > 0.f ? v : 0.f;
                if (d != curd) {
                    if (curd >= 0 && curv > 0.f)
                        atomicMax((unsigned int*)(agg + (size_t)curd * HH + col), __float_as_uint(curv));
                    curd = d;
                    curv = v;
                } else {
                    curv = fmaxf(curv, v);
                }
            }
        }
        if (curd >= 0 && curv > 0.f)
            atomicMax((unsigned int*)(agg + (size_t)curd * HH + col), __float_as_uint(curv));
    }
}

extern "C" void kernel_launch(void* const* d_in, const int* in_sizes, int n_in,
                              void* d_out, int out_size, void* d_ws, size_t ws_size,
                              hipStream_t stream) {
    const float* x = (const float*)d_in[0];
    const int* ei = (const int*)d_in[1];  // int32 per harness contract
    PrepArgs pa;
    const float* b0s[5];
    const float* b1s[5];
    for (int l = 0; l < 5; l++) {
        pa.w0[l] = (const float*)d_in[2 + 4 * l];
        b0s[l] = (const float*)d_in[3 + 4 * l];
        pa.w1[l] = (const float*)d_in[4 + 4 * l];
        b1s[l] = (const float*)d_in[5 + 4 * l];
    }

    int* ssrc = (int*)d_ws;                              // 256 KB
    int* sdst = ssrc + NE;                               // 256 KB
    int* counts = sdst + NE;                             // 4 KB
    int* cursor = counts + 1024;                         // 4 KB
    _Float16* node_ab = (_Float16*)(cursor + 1024);      // [1024][512] fp16, 1 MB
    float* aggA = (float*)(node_ab + 1024 * 512);        // 1 MB
    float* aggB = aggA + NN * HH;                        // 1 MB
    _Float16* wnode = (_Float16*)(aggB + NN * HH);       // 5 x 131072 halfs, 1.25 MB
    _Float16* w2h = wnode + 5 * 131072;                  // 5 x 65536 halfs, 0.63 MB

    hipLaunchKernelGGL(k_prep, dim3(256), dim3(256), 0, stream, pa, wnode, w2h, counts, aggA);
    hipLaunchKernelGGL(k_hist_node0, dim3(256), dim3(256), 0, stream, ei, counts, x, wnode, b0s[0], node_ab);
    hipLaunchKernelGGL(k_scan, dim3(1), dim3(256), 0, stream, counts, cursor);
    hipLaunchKernelGGL(k_scatter, dim3((NE + 255) / 256), dim3(256), 0, stream, ei, cursor, ssrc, sdst);

    float* aggs[5] = {aggA, aggB, aggA, aggB, (float*)d_out};
    for (int l = 0; l < 5; l++) {
        hipLaunchKernelGGL(edge_gemm, dim3(NE / 64), dim3(256), 0, stream,
                           node_ab, ssrc, sdst, w2h + (size_t)l * 65536, b1s[l], aggs[l]);
        if (l < 4)
            hipLaunchKernelGGL(k_node_zero, dim3(252 + 64), dim3(256), 0, stream,
                               aggs[l], wnode + (size_t)(l + 1) * 131072, b0s[l + 1],
                               node_ab, aggs[l + 1]);
    }
}